// Round 13
// baseline (831.387 us; speedup 1.0000x reference)
//
#include <hip/hip_runtime.h>

#define OBS_LEN 8
#define PRED_LEN 12
#define NTHREADS 256
// block = 4 waves; each wave owns 16 samples for the whole recurrence.

typedef __attribute__((ext_vector_type(8))) short short8;  // 8 bf16
typedef __attribute__((ext_vector_type(4))) float floatx4;
typedef __attribute__((ext_vector_type(2))) float floatx2;
typedef __attribute__((ext_vector_type(4))) unsigned int u32x4;
typedef __attribute__((ext_vector_type(2))) unsigned int u32x2;
typedef unsigned short u16;
typedef unsigned int u32;

#define L2E 1.442695040888963f

__device__ __forceinline__ u16 f2bf(float f) {
  __bf16 b = (__bf16)f;
  return __builtin_bit_cast(u16, b);
}
__device__ __forceinline__ float bf2f(u16 h) {
  return __builtin_bit_cast(float, ((u32)h) << 16);
}
__device__ __forceinline__ float rndbf(float f) { return (float)(__bf16)f; }

#if __has_builtin(__builtin_amdgcn_exp2f)
__device__ __forceinline__ float fexp2_(float x) { return __builtin_amdgcn_exp2f(x); }
#else
__device__ __forceinline__ float fexp2_(float x) { return exp2f(x); }
#endif
__device__ __forceinline__ floatx2 exp2v(floatx2 x) {
  floatx2 r;
  r.x = fexp2_(x.x);
  r.y = fexp2_(x.y);
  return r;
}
#if __has_builtin(__builtin_amdgcn_rcpf)
__device__ __forceinline__ floatx2 rcp2(floatx2 x) {  // raw v_rcp ~1ulp
  floatx2 r;
  r.x = __builtin_amdgcn_rcpf(x.x);
  r.y = __builtin_amdgcn_rcpf(x.y);
  return r;
}
#else
__device__ __forceinline__ floatx2 rcp2(floatx2 x) {
  return floatx2{1.0f / x.x, 1.0f / x.y};
}
#endif

__device__ __forceinline__ floatx4 mfma_bf(short8 a, short8 b, floatx4 c) {
  return __builtin_amdgcn_mfma_f32_16x16x32_bf16(a, b, c, 0, 0, 0);
}

// W_hh A-frags, ALL 16 gate-tiles resident (128 regs, MFMA-only -> accum half).
// Tile gt*4+tq covers gate rows (gt*4+tq)*16..+15; lane (q,l16): A[m=l16][k=q*8+j].
__device__ __forceinline__ void load_afh(const float* __restrict__ W,
                                         short8 (&afh)[16][2], int q, int l16) {
#pragma unroll
  for (int tile = 0; tile < 16; ++tile)
#pragma unroll
    for (int kf = 0; kf < 2; ++kf) {
      const float* src = W + (tile * 16 + l16) * 64 + kf * 32 + q * 8;
      const floatx4 w0 = *(const floatx4*)src;
      const floatx4 w1 = *(const floatx4*)(src + 4);
      short8 a;
#pragma unroll
      for (int j = 0; j < 4; ++j) {
        a[j] = (short)f2bf(w0[j]);
        a[j + 4] = (short)f2bf(w1[j]);
      }
      afh[tile][kf] = a;
    }
}

// Stage bf16(W_ih) into LDS with per-row XOR block swizzle (16B block b of row r
// stored at b^(r&7)): the step's read pattern (lanes (q,l16) -> row tile*16+l16,
// block kf*4+q) becomes <=2-way bank aliased.
__device__ __forceinline__ void stage_afx(const float* __restrict__ W,
                                          u16* __restrict__ afxS, int tid) {
  const float* src = W + tid * 64;
  u16* dst = afxS + tid * 64;
  const int rs = tid & 7;
#pragma unroll
  for (int b = 0; b < 8; ++b) {
    const floatx4 w0 = *(const floatx4*)(src + b * 8);
    const floatx4 w1 = *(const floatx4*)(src + b * 8 + 4);
    short8 v;
#pragma unroll
    for (int j = 0; j < 4; ++j) {
      v[j] = (short)f2bf(w0[j]);
      v[j + 4] = (short)f2bf(w1[j]);
    }
    *(short8*)(dst + ((b ^ rs) * 8)) = v;
  }
}

// One LSTM step, NO barrier. All data for this wave's 16 samples is wave-local:
// h lives in a wave-private LDS region (same-wave ds ordering = program order),
// x is built in-register, rel comes from 2 aex-MFMAs on the just-read h B-frags.
template <bool REL>
__device__ __forceinline__ void step(
    u16* __restrict__ hw, const u16* __restrict__ afxS,
    const float* __restrict__ biasP,
    const u32* __restrict__ ewpkP, const float* __restrict__ ebvP,
    const float* __restrict__ posrow,
    const short8 (&afh)[16][2], const short8 (&aex)[2],
    floatx2 (&c)[4][2],
    float* __restrict__ outp, float b2p0, float b2p1,
    int q, int l16, int wv) {
  const int sw = l16 & 7;
  const u16* hr = hw + l16 * 64;
  const short8 hb0 = *(const short8*)(hr + ((q ^ sw) * 8));
  const short8 hb1 = *(const short8*)(hr + (((4 + q) ^ sw) * 8));
  float rb0, rb1;
  if (REL) {
    floatx4 z = {0.f, 0.f, 0.f, 0.f};
    z = mfma_bf(aex[0], hb0, z);
    z = mfma_bf(aex[1], hb1, z);
    const float r0 = __shfl(z[0], l16) + b2p0;  // rel rows live on q==0 lanes
    const float r1 = __shfl(z[1], l16) + b2p1;
    if (q == 0) *(floatx2*)(outp + l16 * 2) = floatx2{r0, r1};
    rb0 = rndbf(r0);
    rb1 = rndbf(r1);
  } else {
    const floatx2 rr = *(const floatx2*)(posrow + (wv * 16 + l16) * 2);
    rb0 = rndbf(rr.x);
    rb1 = rndbf(rr.y);
  }
  // x B-frags in-register for k-slices [8q,8q+8) and [32+8q,+8) of this sample
  short8 xb0, xb1;
  {
    const u32x4 e0a = *(const u32x4*)(ewpkP + q * 8);
    const u32x4 e0b = *(const u32x4*)(ewpkP + q * 8 + 4);
    const u32x4 e1a = *(const u32x4*)(ewpkP + 32 + q * 8);
    const u32x4 e1b = *(const u32x4*)(ewpkP + 32 + q * 8 + 4);
    const floatx4 b0a = *(const floatx4*)(ebvP + q * 8);
    const floatx4 b0b = *(const floatx4*)(ebvP + q * 8 + 4);
    const floatx4 b1a = *(const floatx4*)(ebvP + 32 + q * 8);
    const floatx4 b1b = *(const floatx4*)(ebvP + 32 + q * 8 + 4);
#pragma unroll
    for (int j = 0; j < 4; ++j) {
      u32 p = e0a[j];
      xb0[j] = (short)f2bf(rb0 * bf2f((u16)(p & 0xffffu)) +
                           (rb1 * bf2f((u16)(p >> 16)) + b0a[j]));
      p = e0b[j];
      xb0[j + 4] = (short)f2bf(rb0 * bf2f((u16)(p & 0xffffu)) +
                               (rb1 * bf2f((u16)(p >> 16)) + b0b[j]));
      p = e1a[j];
      xb1[j] = (short)f2bf(rb0 * bf2f((u16)(p & 0xffffu)) +
                           (rb1 * bf2f((u16)(p >> 16)) + b1a[j]));
      p = e1b[j];
      xb1[j + 4] = (short)f2bf(rb0 * bf2f((u16)(p & 0xffffu)) +
                               (rb1 * bf2f((u16)(p >> 16)) + b1b[j]));
    }
  }
  // tile-quad loop: gates i,f,g,o of units tq*16+q*4+{0..3} for sample l16
#pragma unroll
  for (int tq = 0; tq < 4; ++tq) {
    floatx4 acc[4];
#pragma unroll
    for (int gt = 0; gt < 4; ++gt) {
      const floatx4 bias = *(const floatx4*)(biasP + gt * 64 + tq * 16 + q * 4);
      acc[gt] = mfma_bf(afh[gt * 4 + tq][0], hb0, bias);
    }
#pragma unroll
    for (int gt = 0; gt < 4; ++gt) {
      const int row = (gt * 4 + tq) * 16 + l16;
      const short8 ax0 = *(const short8*)(afxS + row * 64 + ((q ^ sw) * 8));
      acc[gt] = mfma_bf(ax0, xb0, acc[gt]);
    }
#pragma unroll
    for (int gt = 0; gt < 4; ++gt)
      acc[gt] = mfma_bf(afh[gt * 4 + tq][1], hb1, acc[gt]);
#pragma unroll
    for (int gt = 0; gt < 4; ++gt) {
      const int row = (gt * 4 + tq) * 16 + l16;
      const short8 ax1 = *(const short8*)(afxS + row * 64 + (((4 + q) ^ sw) * 8));
      acc[gt] = mfma_bf(ax1, xb1, acc[gt]);
    }
    u32 hpk[2];
#pragma unroll
    for (int p = 0; p < 2; ++p) {
      const floatx2 iv = {acc[0][2 * p], acc[0][2 * p + 1]};
      const floatx2 fv = {acc[1][2 * p], acc[1][2 * p + 1]};
      const floatx2 gv = {acc[2][2 * p], acc[2][2 * p + 1]};
      const floatx2 ov = {acc[3][2 * p], acc[3][2 * p + 1]};
      const floatx2 ei = exp2v(iv * -L2E);
      const floatx2 ef = exp2v(fv * -L2E);
      const floatx2 eg = exp2v(gv * (2.0f * L2E));
      const floatx2 eo = exp2v(ov * -L2E);
      const floatx2 A = ei + 1.0f;   // 1/sig(i)
      const floatx2 F = ef + 1.0f;   // 1/sig(f)
      const floatx2 Bg = eg + 1.0f;  // tanh(g) = (eg-1)/Bg
      const floatx2 P = A * Bg;
      const floatx2 num = c[tq][p] * P + (eg - 1.0f) * F;
      const floatx2 cn = num * rcp2(F * P);
      c[tq][p] = cn;
      const floatx2 ec = exp2v(cn * (2.0f * L2E));
      const floatx2 h = (ec - 1.0f) * rcp2((eo + 1.0f) * (ec + 1.0f));
      hpk[p] = (u32)f2bf(h.x) | ((u32)f2bf(h.y) << 16);
    }
    // write h units tq*16+q*4..+3 of sample l16 (block 2tq+(q>>1), half q&1)
    *(u32x2*)(hw + l16 * 64 + (((2 * tq + (q >> 1)) ^ sw) * 8) + (q & 1) * 4) =
        u32x2{hpk[0], hpk[1]};
  }
}

// (256,2): 256 unified regs/wave. afh(128)+aex(8) MFMA-only -> accum side;
// VALU-touched (c16 + transients ~100) on arch side; accum_offset flexible.
__global__ void __launch_bounds__(NTHREADS, 2)
lstm_kernel(const float* __restrict__ obs_rel,
            const float* __restrict__ enc_emb_w, const float* __restrict__ enc_emb_b,
            const float* __restrict__ enc_w_ih, const float* __restrict__ enc_w_hh,
            const float* __restrict__ enc_b_ih, const float* __restrict__ enc_b_hh,
            const float* __restrict__ dec_emb_w, const float* __restrict__ dec_emb_b,
            const float* __restrict__ dec_w_ih, const float* __restrict__ dec_w_hh,
            const float* __restrict__ dec_b_ih, const float* __restrict__ dec_b_hh,
            const float* __restrict__ h2p_w, const float* __restrict__ h2p_b,
            float* __restrict__ out, int batch) {
  __shared__ __align__(16) u16 afxS[256 * 64];      // 32 KB, swizzled bf16 W_ih
  __shared__ __align__(16) u16 hS[4][16 * 64];      // 8 KB, wave-private h
  __shared__ __align__(16) float posS[OBS_LEN][128];
  __shared__ __align__(16) float biasS[2][256];
  __shared__ __align__(16) u32 ewpkS[2][64];
  __shared__ __align__(16) float ebvS[2][64];

  const int tid = threadIdx.x;
  const int wv = tid >> 6, lane = tid & 63;
  const int q = lane >> 4, l16 = lane & 15;
  const long S0 = (long)blockIdx.x * 64;

  stage_afx(enc_w_ih, afxS, tid);
  {  // stage all 8 encoder-step position rows (coalesced float4)
    const int t = tid >> 5, i = tid & 31;
    *(floatx4*)&posS[t][i * 4] =
        *(const floatx4*)(obs_rel + (long)t * batch * 2 + S0 * 2 + i * 4);
  }
  biasS[0][tid] = enc_b_ih[tid] + enc_b_hh[tid];
  biasS[1][tid] = dec_b_ih[tid] + dec_b_hh[tid];
  if (tid < 64) {
    ewpkS[0][tid] = (u32)f2bf(enc_emb_w[tid * 2]) |
                    ((u32)f2bf(enc_emb_w[tid * 2 + 1]) << 16);
    ewpkS[1][tid] = (u32)f2bf(dec_emb_w[tid * 2]) |
                    ((u32)f2bf(dec_emb_w[tid * 2 + 1]) << 16);
    ebvS[0][tid] = enc_emb_b[tid];
    ebvS[1][tid] = dec_emb_b[tid];
  }
  for (int i = tid; i < 4 * 16 * 64 / 2; i += NTHREADS) ((u32*)&hS[0][0])[i] = 0;

  short8 afh[16][2], aex[2];
  floatx2 c[4][2];
  load_afh(enc_w_hh, afh, q, l16);
#pragma unroll
  for (int t = 0; t < 4; ++t) c[t][0] = c[t][1] = floatx2{0.f, 0.f};
  aex[0] = aex[1] = short8{0, 0, 0, 0, 0, 0, 0, 0};
  const float b2p0 = h2p_b[0], b2p1 = h2p_b[1];
  u16* hw = &hS[wv][0];
  __syncthreads();  // staging visible; last block barrier until phase switch

  // ---- encoder: 8 steps, barrier-free
#pragma unroll 1
  for (int t = 0; t < OBS_LEN; ++t)
    step<false>(hw, afxS, biasS[0], ewpkS[0], ebvS[0], posS[t], afh, aex, c,
                nullptr, b2p0, b2p1, q, l16, wv);

  // ---- phase switch: restage afxS (only block-shared mutable data)
  __syncthreads();
  stage_afx(dec_w_ih, afxS, tid);
  __syncthreads();
  load_afh(dec_w_hh, afh, q, l16);
#pragma unroll
  for (int t = 0; t < 4; ++t) c[t][0] = c[t][1] = floatx2{0.f, 0.f};
#pragma unroll
  for (int kf = 0; kf < 2; ++kf) {
    short8 a = {0, 0, 0, 0, 0, 0, 0, 0};
    if (l16 < 2) {
      const float* src = h2p_w + l16 * 64 + kf * 32 + q * 8;
#pragma unroll
      for (int j = 0; j < 8; ++j) a[j] = (short)f2bf(src[j]);
    }
    aex[kf] = a;
  }

  // decoder step 0: x = emb_dec(bf16(last_rel)), h = h_enc, c = 0
  step<false>(hw, afxS, biasS[1], ewpkS[1], ebvS[1], posS[7], afh, aex, c,
              nullptr, b2p0, b2p1, q, l16, wv);

  // decoder steps 1..11: rel_{j-1} via aex-MFMA -> out + feedback, barrier-free
#pragma unroll 1
  for (int j = 1; j < PRED_LEN; ++j)
    step<true>(hw, afxS, biasS[1], ewpkS[1], ebvS[1], nullptr, afh, aex, c,
               out + (long)(j - 1) * batch * 2 + (S0 + wv * 16) * 2,
               b2p0, b2p1, q, l16, wv);

  // ---- trailing output: rel_pos[11] from h_12
  {
    const int sw = l16 & 7;
    const u16* hr = hw + l16 * 64;
    const short8 hb0 = *(const short8*)(hr + ((q ^ sw) * 8));
    const short8 hb1 = *(const short8*)(hr + (((4 + q) ^ sw) * 8));
    floatx4 z = {0.f, 0.f, 0.f, 0.f};
    z = mfma_bf(aex[0], hb0, z);
    z = mfma_bf(aex[1], hb1, z);
    if (q == 0) {
      float* outp = out + (long)(PRED_LEN - 1) * batch * 2 + (S0 + wv * 16) * 2;
      *(floatx2*)(outp + l16 * 2) = floatx2{z[0] + b2p0, z[1] + b2p1};
    }
  }
}

extern "C" void kernel_launch(void* const* d_in, const int* in_sizes, int n_in,
                              void* d_out, int out_size, void* d_ws, size_t ws_size,
                              hipStream_t stream) {
  const float* obs_rel = (const float*)d_in[1];
  const int batch = in_sizes[1] / (OBS_LEN * 2);  // 65536

  const int blocks = batch / 64;  // 1024
  hipLaunchKernelGGL(lstm_kernel, dim3(blocks), dim3(NTHREADS), 0, stream,
                     obs_rel,
                     (const float*)d_in[2], (const float*)d_in[3],
                     (const float*)d_in[4], (const float*)d_in[5],
                     (const float*)d_in[6], (const float*)d_in[7],
                     (const float*)d_in[8], (const float*)d_in[9],
                     (const float*)d_in[10], (const float*)d_in[11],
                     (const float*)d_in[12], (const float*)d_in[13],
                     (const float*)d_in[14], (const float*)d_in[15],
                     (float*)d_out, batch);
}

// Round 14
// 764.097 us; speedup vs baseline: 1.0881x; 1.0881x over previous
//
#include <hip/hip_runtime.h>

#define OBS_LEN 8
#define PRED_LEN 12
#define NTHREADS 256
// 4 waves/block; each wave owns 16 samples end-to-end. No recurrence barriers.

typedef __attribute__((ext_vector_type(8))) short short8;  // 8 bf16
typedef __attribute__((ext_vector_type(4))) float floatx4;
typedef __attribute__((ext_vector_type(2))) float floatx2;
typedef __attribute__((ext_vector_type(4))) unsigned int u32x4;
typedef __attribute__((ext_vector_type(2))) unsigned int u32x2;
typedef unsigned short u16;
typedef unsigned int u32;

#define L2E 1.442695040888963f

__device__ __forceinline__ u16 f2bf(float f) {
  __bf16 b = (__bf16)f;
  return __builtin_bit_cast(u16, b);
}
__device__ __forceinline__ float bf2f(u16 h) {
  return __builtin_bit_cast(float, ((u32)h) << 16);
}
__device__ __forceinline__ float rndbf(float f) { return (float)(__bf16)f; }

#if __has_builtin(__builtin_amdgcn_exp2f)
__device__ __forceinline__ float fexp2_(float x) { return __builtin_amdgcn_exp2f(x); }
#else
__device__ __forceinline__ float fexp2_(float x) { return exp2f(x); }
#endif
__device__ __forceinline__ floatx2 exp2v(floatx2 x) {
  floatx2 r;
  r.x = fexp2_(x.x);
  r.y = fexp2_(x.y);
  return r;
}
#if __has_builtin(__builtin_amdgcn_rcpf)
__device__ __forceinline__ floatx2 rcp2(floatx2 x) {  // raw v_rcp ~1ulp
  floatx2 r;
  r.x = __builtin_amdgcn_rcpf(x.x);
  r.y = __builtin_amdgcn_rcpf(x.y);
  return r;
}
#else
__device__ __forceinline__ floatx2 rcp2(floatx2 x) {
  return floatx2{1.0f / x.x, 1.0f / x.y};
}
#endif

__device__ __forceinline__ floatx4 mfma_bf(short8 a, short8 b, floatx4 c) {
  return __builtin_amdgcn_mfma_f32_16x16x32_bf16(a, b, c, 0, 0, 0);
}

// Stage bf16(W) into LDS with per-row XOR block swizzle (16B block b of row r
// stored at b^(r&7)): the step's read lanes (q,l16)->row tile*16+l16, block
// (kf*4+q)^(l16&7) land <=2-way per bank (free). Weights stay in LDS, NOT in
// registers: R13 proved a VALU-built 128-reg A-frag array lives on the arch
// side of the unified file and spills catastrophically (505MB scratch writes).
__device__ __forceinline__ void stage_w(const float* __restrict__ W,
                                        u16* __restrict__ dst, int tid) {
  const float* src = W + tid * 64;
  u16* d = dst + tid * 64;
  const int rs = tid & 7;
#pragma unroll
  for (int b = 0; b < 8; ++b) {
    const floatx4 w0 = *(const floatx4*)(src + b * 8);
    const floatx4 w1 = *(const floatx4*)(src + b * 8 + 4);
    short8 v;
#pragma unroll
    for (int j = 0; j < 4; ++j) {
      v[j] = (short)f2bf(w0[j]);
      v[j + 4] = (short)f2bf(w1[j]);
    }
    *(short8*)(d + ((b ^ rs) * 8)) = v;
  }
}

// One LSTM step, NO barrier. All state for this wave's 16 samples is wave-local:
// h in a wave-private LDS region (same-wave ds ordering = program order,
// R13-verified), x built in-register, rel via 2 aex-MFMAs, weights streamed
// from the block-shared swizzled LDS image per use (transient regs only).
template <bool REL>
__device__ __forceinline__ void step(
    u16* __restrict__ hw,
    const u16* __restrict__ whhS, const u16* __restrict__ wihS,
    const float* __restrict__ biasS,
    const u32* __restrict__ ewpkS, const float* __restrict__ ebvS,
    const float* __restrict__ posrow,
    const short8 (&aex)[2], floatx2 (&c)[4][2],
    float* __restrict__ outp, float b2p0, float b2p1,
    int q, int l16) {
  const int sw = l16 & 7;
  const u16* hr = hw + l16 * 64;
  const short8 hb0 = *(const short8*)(hr + ((q ^ sw) * 8));
  const short8 hb1 = *(const short8*)(hr + (((4 + q) ^ sw) * 8));
  float rb0, rb1;
  if (REL) {
    floatx4 z = {0.f, 0.f, 0.f, 0.f};
    z = mfma_bf(aex[0], hb0, z);
    z = mfma_bf(aex[1], hb1, z);
    const float r0 = __shfl(z[0], l16) + b2p0;  // rel rows live on q==0 lanes
    const float r1 = __shfl(z[1], l16) + b2p1;
    if (q == 0) *(floatx2*)(outp + l16 * 2) = floatx2{r0, r1};
    rb0 = rndbf(r0);
    rb1 = rndbf(r1);
  } else {
    const floatx2 rr = *(const floatx2*)(posrow + l16 * 2);
    rb0 = rndbf(rr.x);
    rb1 = rndbf(rr.y);
  }
  // x B-frags in-register for k-slices [8q,8q+8) and [32+8q,+8) of this sample
  short8 xb0, xb1;
  {
    const u32x4 e0a = *(const u32x4*)(ewpkS + q * 8);
    const u32x4 e0b = *(const u32x4*)(ewpkS + q * 8 + 4);
    const u32x4 e1a = *(const u32x4*)(ewpkS + 32 + q * 8);
    const u32x4 e1b = *(const u32x4*)(ewpkS + 32 + q * 8 + 4);
    const floatx4 b0a = *(const floatx4*)(ebvS + q * 8);
    const floatx4 b0b = *(const floatx4*)(ebvS + q * 8 + 4);
    const floatx4 b1a = *(const floatx4*)(ebvS + 32 + q * 8);
    const floatx4 b1b = *(const floatx4*)(ebvS + 32 + q * 8 + 4);
#pragma unroll
    for (int j = 0; j < 4; ++j) {
      u32 p = e0a[j];
      xb0[j] = (short)f2bf(rb0 * bf2f((u16)(p & 0xffffu)) +
                           (rb1 * bf2f((u16)(p >> 16)) + b0a[j]));
      p = e0b[j];
      xb0[j + 4] = (short)f2bf(rb0 * bf2f((u16)(p & 0xffffu)) +
                               (rb1 * bf2f((u16)(p >> 16)) + b0b[j]));
      p = e1a[j];
      xb1[j] = (short)f2bf(rb0 * bf2f((u16)(p & 0xffffu)) +
                           (rb1 * bf2f((u16)(p >> 16)) + b1a[j]));
      p = e1b[j];
      xb1[j + 4] = (short)f2bf(rb0 * bf2f((u16)(p & 0xffffu)) +
                               (rb1 * bf2f((u16)(p >> 16)) + b1b[j]));
    }
  }
  // tile-quad loop: gates i,f,g,o of units tq*16+q*4+{0..3} for sample l16
#pragma unroll
  for (int tq = 0; tq < 4; ++tq) {
    floatx4 acc[4];
#pragma unroll
    for (int gt = 0; gt < 4; ++gt) {
      const int row = (gt * 4 + tq) * 16 + l16;
      const floatx4 bias = *(const floatx4*)(biasS + gt * 64 + tq * 16 + q * 4);
      const short8 ah0 = *(const short8*)(whhS + row * 64 + ((q ^ sw) * 8));
      acc[gt] = mfma_bf(ah0, hb0, bias);
    }
#pragma unroll
    for (int gt = 0; gt < 4; ++gt) {
      const int row = (gt * 4 + tq) * 16 + l16;
      const short8 ax0 = *(const short8*)(wihS + row * 64 + ((q ^ sw) * 8));
      acc[gt] = mfma_bf(ax0, xb0, acc[gt]);
    }
#pragma unroll
    for (int gt = 0; gt < 4; ++gt) {
      const int row = (gt * 4 + tq) * 16 + l16;
      const short8 ah1 = *(const short8*)(whhS + row * 64 + (((4 + q) ^ sw) * 8));
      acc[gt] = mfma_bf(ah1, hb1, acc[gt]);
    }
#pragma unroll
    for (int gt = 0; gt < 4; ++gt) {
      const int row = (gt * 4 + tq) * 16 + l16;
      const short8 ax1 = *(const short8*)(wihS + row * 64 + (((4 + q) ^ sw) * 8));
      acc[gt] = mfma_bf(ax1, xb1, acc[gt]);
    }
    u32 hpk[2];
#pragma unroll
    for (int p = 0; p < 2; ++p) {
      const floatx2 iv = {acc[0][2 * p], acc[0][2 * p + 1]};
      const floatx2 fv = {acc[1][2 * p], acc[1][2 * p + 1]};
      const floatx2 gv = {acc[2][2 * p], acc[2][2 * p + 1]};
      const floatx2 ov = {acc[3][2 * p], acc[3][2 * p + 1]};
      const floatx2 ei = exp2v(iv * -L2E);
      const floatx2 ef = exp2v(fv * -L2E);
      const floatx2 eg = exp2v(gv * (2.0f * L2E));
      const floatx2 eo = exp2v(ov * -L2E);
      const floatx2 A = ei + 1.0f;   // 1/sig(i)
      const floatx2 F = ef + 1.0f;   // 1/sig(f)
      const floatx2 Bg = eg + 1.0f;  // tanh(g) = (eg-1)/Bg
      const floatx2 P = A * Bg;
      const floatx2 num = c[tq][p] * P + (eg - 1.0f) * F;
      const floatx2 cn = num * rcp2(F * P);
      c[tq][p] = cn;
      const floatx2 ec = exp2v(cn * (2.0f * L2E));
      const floatx2 h = (ec - 1.0f) * rcp2((eo + 1.0f) * (ec + 1.0f));
      hpk[p] = (u32)f2bf(h.x) | ((u32)f2bf(h.y) << 16);
    }
    // write h units tq*16+q*4..+3 of sample l16 (block 2tq+(q>>1), half q&1)
    *(u32x2*)(hw + l16 * 64 + (((2 * tq + (q >> 1)) ^ sw) * 8) + (q & 1) * 4) =
        u32x2{hpk[0], hpk[1]};
  }
}

// (256,2): arch half = 128 regs; working set here is all-transient (~80 peak,
// no persistent weight arrays) -> no spill. LDS 73.5 KB -> 2 blocks/CU.
__global__ void __launch_bounds__(NTHREADS, 2)
lstm_kernel(const float* __restrict__ obs_rel,
            const float* __restrict__ enc_emb_w, const float* __restrict__ enc_emb_b,
            const float* __restrict__ enc_w_ih, const float* __restrict__ enc_w_hh,
            const float* __restrict__ enc_b_ih, const float* __restrict__ enc_b_hh,
            const float* __restrict__ dec_emb_w, const float* __restrict__ dec_emb_b,
            const float* __restrict__ dec_w_ih, const float* __restrict__ dec_w_hh,
            const float* __restrict__ dec_b_ih, const float* __restrict__ dec_b_hh,
            const float* __restrict__ h2p_w, const float* __restrict__ h2p_b,
            float* __restrict__ out, int batch) {
  __shared__ __align__(16) u16 whhS[256 * 64];  // 32 KB swizzled bf16 W_hh
  __shared__ __align__(16) u16 wihS[256 * 64];  // 32 KB swizzled bf16 W_ih
  __shared__ __align__(16) u16 hS[4][16 * 64];  // 8 KB wave-private h
  __shared__ __align__(16) float biasS[256];    // current-phase gate bias
  __shared__ __align__(16) u32 ewpkS[64];       // current-phase packed emb w
  __shared__ __align__(16) float ebvS[64];      // current-phase emb bias

  const int tid = threadIdx.x;
  const int wv = tid >> 6, lane = tid & 63;
  const int q = lane >> 4, l16 = lane & 15;
  const long S0 = (long)blockIdx.x * 64;

  stage_w(enc_w_hh, whhS, tid);
  stage_w(enc_w_ih, wihS, tid);
  biasS[tid] = enc_b_ih[tid] + enc_b_hh[tid];
  if (tid < 64) {
    ewpkS[tid] = (u32)f2bf(enc_emb_w[tid * 2]) |
                 ((u32)f2bf(enc_emb_w[tid * 2 + 1]) << 16);
    ebvS[tid] = enc_emb_b[tid];
  }
  for (int i = tid; i < 4 * 16 * 64 / 2; i += NTHREADS) ((u32*)&hS[0][0])[i] = 0;

  short8 aex[2];
  floatx2 c[4][2];
#pragma unroll
  for (int t = 0; t < 4; ++t) c[t][0] = c[t][1] = floatx2{0.f, 0.f};
  aex[0] = aex[1] = short8{0, 0, 0, 0, 0, 0, 0, 0};
  const float b2p0 = h2p_b[0], b2p1 = h2p_b[1];
  u16* hw = &hS[wv][0];
  __syncthreads();  // staging visible; no more barriers until phase switch

  // ---- encoder: 8 steps, barrier-free (pos read straight from global, L2-warm)
#pragma unroll 1
  for (int t = 0; t < OBS_LEN; ++t)
    step<false>(hw, whhS, wihS, biasS, ewpkS, ebvS,
                obs_rel + (long)t * batch * 2 + (S0 + wv * 16) * 2,
                aex, c, nullptr, b2p0, b2p1, q, l16);

  // ---- phase switch: restage decoder weights/tables (2 barriers total)
  __syncthreads();
  stage_w(dec_w_hh, whhS, tid);
  stage_w(dec_w_ih, wihS, tid);
  biasS[tid] = dec_b_ih[tid] + dec_b_hh[tid];
  if (tid < 64) {
    ewpkS[tid] = (u32)f2bf(dec_emb_w[tid * 2]) |
                 ((u32)f2bf(dec_emb_w[tid * 2 + 1]) << 16);
    ebvS[tid] = dec_emb_b[tid];
  }
  __syncthreads();
#pragma unroll
  for (int t = 0; t < 4; ++t) c[t][0] = c[t][1] = floatx2{0.f, 0.f};
#pragma unroll
  for (int kf = 0; kf < 2; ++kf) {
    short8 a = {0, 0, 0, 0, 0, 0, 0, 0};
    if (l16 < 2) {
      const float* src = h2p_w + l16 * 64 + kf * 32 + q * 8;
#pragma unroll
      for (int j = 0; j < 8; ++j) a[j] = (short)f2bf(src[j]);
    }
    aex[kf] = a;
  }

  // decoder step 0: x = emb_dec(bf16(last_rel)), h = h_enc, c = 0
  step<false>(hw, whhS, wihS, biasS, ewpkS, ebvS,
              obs_rel + (long)7 * batch * 2 + (S0 + wv * 16) * 2,
              aex, c, nullptr, b2p0, b2p1, q, l16);

  // decoder steps 1..11: rel_{j-1} via aex-MFMA -> out + feedback, barrier-free
#pragma unroll 1
  for (int j = 1; j < PRED_LEN; ++j)
    step<true>(hw, whhS, wihS, biasS, ewpkS, ebvS, nullptr, aex, c,
               out + (long)(j - 1) * batch * 2 + (S0 + wv * 16) * 2,
               b2p0, b2p1, q, l16);

  // ---- trailing output: rel_pos[11] from h_12
  {
    const int sw = l16 & 7;
    const u16* hr = hw + l16 * 64;
    const short8 hb0 = *(const short8*)(hr + ((q ^ sw) * 8));
    const short8 hb1 = *(const short8*)(hr + (((4 + q) ^ sw) * 8));
    floatx4 z = {0.f, 0.f, 0.f, 0.f};
    z = mfma_bf(aex[0], hb0, z);
    z = mfma_bf(aex[1], hb1, z);
    if (q == 0) {
      float* outp = out + (long)(PRED_LEN - 1) * batch * 2 + (S0 + wv * 16) * 2;
      *(floatx2*)(outp + l16 * 2) = floatx2{z[0] + b2p0, z[1] + b2p1};
    }
  }
}

extern "C" void kernel_launch(void* const* d_in, const int* in_sizes, int n_in,
                              void* d_out, int out_size, void* d_ws, size_t ws_size,
                              hipStream_t stream) {
  const float* obs_rel = (const float*)d_in[1];
  const int batch = in_sizes[1] / (OBS_LEN * 2);  // 65536

  const int blocks = batch / 64;  // 1024
  hipLaunchKernelGGL(lstm_kernel, dim3(blocks), dim3(NTHREADS), 0, stream,
                     obs_rel,
                     (const float*)d_in[2], (const float*)d_in[3],
                     (const float*)d_in[4], (const float*)d_in[5],
                     (const float*)d_in[6], (const float*)d_in[7],
                     (const float*)d_in[8], (const float*)d_in[9],
                     (const float*)d_in[10], (const float*)d_in[11],
                     (const float*)d_in[12], (const float*)d_in[13],
                     (const float*)d_in[14], (const float*)d_in[15],
                     (float*)d_out, batch);
}

// Round 15
// 240.302 us; speedup vs baseline: 3.4598x; 3.1797x over previous
//
#include <hip/hip_runtime.h>

#define OBS_LEN 8
#define PRED_LEN 12
#define NTHREADS 256
// 4 waves/block; each wave owns 16 samples end-to-end. No recurrence barriers.

typedef __attribute__((ext_vector_type(8))) short short8;  // 8 bf16
typedef __attribute__((ext_vector_type(4))) float floatx4;
typedef __attribute__((ext_vector_type(2))) float floatx2;
typedef __attribute__((ext_vector_type(4))) unsigned int u32x4;
typedef __attribute__((ext_vector_type(2))) unsigned int u32x2;
typedef unsigned short u16;
typedef unsigned int u32;

#define L2E 1.442695040888963f

__device__ __forceinline__ u16 f2bf(float f) {
  __bf16 b = (__bf16)f;
  return __builtin_bit_cast(u16, b);
}
__device__ __forceinline__ float bf2f(u16 h) {
  return __builtin_bit_cast(float, ((u32)h) << 16);
}
__device__ __forceinline__ float rndbf(float f) { return (float)(__bf16)f; }

#if __has_builtin(__builtin_amdgcn_exp2f)
__device__ __forceinline__ float fexp2_(float x) { return __builtin_amdgcn_exp2f(x); }
#else
__device__ __forceinline__ float fexp2_(float x) { return exp2f(x); }
#endif
__device__ __forceinline__ floatx2 exp2v(floatx2 x) {
  floatx2 r;
  r.x = fexp2_(x.x);
  r.y = fexp2_(x.y);
  return r;
}
#if __has_builtin(__builtin_amdgcn_rcpf)
__device__ __forceinline__ floatx2 rcp2(floatx2 x) {  // raw v_rcp ~1ulp
  floatx2 r;
  r.x = __builtin_amdgcn_rcpf(x.x);
  r.y = __builtin_amdgcn_rcpf(x.y);
  return r;
}
#else
__device__ __forceinline__ floatx2 rcp2(floatx2 x) {
  return floatx2{1.0f / x.x, 1.0f / x.y};
}
#endif

__device__ __forceinline__ floatx4 mfma_bf(short8 a, short8 b, floatx4 c) {
  return __builtin_amdgcn_mfma_f32_16x16x32_bf16(a, b, c, 0, 0, 0);
}

// Stage bf16(W) into LDS with per-row XOR block swizzle (16B block b of row r
// stored at b^(r&7)): step-time read lanes land <=2-way per bank (free).
__device__ __forceinline__ void stage_w(const float* __restrict__ W,
                                        u16* __restrict__ dst, int tid) {
  const float* src = W + tid * 64;
  u16* d = dst + tid * 64;
  const int rs = tid & 7;
#pragma unroll
  for (int b = 0; b < 8; ++b) {
    const floatx4 w0 = *(const floatx4*)(src + b * 8);
    const floatx4 w1 = *(const floatx4*)(src + b * 8 + 4);
    short8 v;
#pragma unroll
    for (int j = 0; j < 4; ++j) {
      v[j] = (short)f2bf(w0[j]);
      v[j + 4] = (short)f2bf(w1[j]);
    }
    *(short8*)(d + ((b ^ rs) * 8)) = v;
  }
}

// One LSTM step, NO barrier. h in a wave-private LDS region (same-wave ds
// ordering = program order), x in-register, rel via 2 aex-MFMAs, weights
// streamed from the block-shared swizzled LDS image.
// The tq loop is FORCED non-unrolled: R13 (505MB) and R14 (410MB) proved the
// scheduler hoists the unrolled body's 64 ds_read_b128 into ~30 concurrent
// 4-reg live ranges, exhausting the 128-reg arch half and spilling the
// loop-carried state every step. unroll 1 caps the exposed window at one
// iteration (16 A-frag loads) -> peak ~100 arch regs.
template <bool REL>
__device__ __forceinline__ void step(
    u16* __restrict__ hw,
    const u16* __restrict__ whhS, const u16* __restrict__ wihS,
    const float* __restrict__ biasS,
    const u32* __restrict__ ewpkS, const float* __restrict__ ebvS,
    const float* __restrict__ posrow,
    const short8 (&aex)[2], floatx2 (&c)[4][2],
    float* __restrict__ outp, float b2p0, float b2p1,
    int q, int l16) {
  const int sw = l16 & 7;
  const u16* hr = hw + l16 * 64;
  const short8 hb0 = *(const short8*)(hr + ((q ^ sw) * 8));
  const short8 hb1 = *(const short8*)(hr + (((4 + q) ^ sw) * 8));
  float rb0, rb1;
  if (REL) {
    floatx4 z = {0.f, 0.f, 0.f, 0.f};
    z = mfma_bf(aex[0], hb0, z);
    z = mfma_bf(aex[1], hb1, z);
    const float r0 = __shfl(z[0], l16) + b2p0;  // rel rows live on q==0 lanes
    const float r1 = __shfl(z[1], l16) + b2p1;
    if (q == 0) *(floatx2*)(outp + l16 * 2) = floatx2{r0, r1};
    rb0 = rndbf(r0);
    rb1 = rndbf(r1);
  } else {
    const floatx2 rr = *(const floatx2*)(posrow + l16 * 2);
    rb0 = rndbf(rr.x);
    rb1 = rndbf(rr.y);
  }
  // x B-frags in-register for k-slices [8q,8q+8) and [32+8q,+8) of this sample
  short8 xb0, xb1;
  {
    const u32x4 e0a = *(const u32x4*)(ewpkS + q * 8);
    const u32x4 e0b = *(const u32x4*)(ewpkS + q * 8 + 4);
    const u32x4 e1a = *(const u32x4*)(ewpkS + 32 + q * 8);
    const u32x4 e1b = *(const u32x4*)(ewpkS + 32 + q * 8 + 4);
    const floatx4 b0a = *(const floatx4*)(ebvS + q * 8);
    const floatx4 b0b = *(const floatx4*)(ebvS + q * 8 + 4);
    const floatx4 b1a = *(const floatx4*)(ebvS + 32 + q * 8);
    const floatx4 b1b = *(const floatx4*)(ebvS + 32 + q * 8 + 4);
#pragma unroll
    for (int j = 0; j < 4; ++j) {
      u32 p = e0a[j];
      xb0[j] = (short)f2bf(rb0 * bf2f((u16)(p & 0xffffu)) +
                           (rb1 * bf2f((u16)(p >> 16)) + b0a[j]));
      p = e0b[j];
      xb0[j + 4] = (short)f2bf(rb0 * bf2f((u16)(p & 0xffffu)) +
                               (rb1 * bf2f((u16)(p >> 16)) + b0b[j]));
      p = e1a[j];
      xb1[j] = (short)f2bf(rb0 * bf2f((u16)(p & 0xffffu)) +
                           (rb1 * bf2f((u16)(p >> 16)) + b1a[j]));
      p = e1b[j];
      xb1[j + 4] = (short)f2bf(rb0 * bf2f((u16)(p & 0xffffu)) +
                               (rb1 * bf2f((u16)(p >> 16)) + b1b[j]));
    }
  }
  // tile-quad loop: gates i,f,g,o of units tq*16+q*4+{0..3} for sample l16
#pragma unroll 1
  for (int tq = 0; tq < 4; ++tq) {
    const int rbase = tq * 16 + l16;
    floatx4 acc[4];
#pragma unroll
    for (int gt = 0; gt < 4; ++gt) {
      const floatx4 bias = *(const floatx4*)(biasS + gt * 64 + tq * 16 + q * 4);
      const short8 ah0 =
          *(const short8*)(whhS + (gt * 64 + rbase) * 64 + ((q ^ sw) * 8));
      acc[gt] = mfma_bf(ah0, hb0, bias);
    }
#pragma unroll
    for (int gt = 0; gt < 4; ++gt) {
      const short8 ax0 =
          *(const short8*)(wihS + (gt * 64 + rbase) * 64 + ((q ^ sw) * 8));
      acc[gt] = mfma_bf(ax0, xb0, acc[gt]);
    }
#pragma unroll
    for (int gt = 0; gt < 4; ++gt) {
      const short8 ah1 =
          *(const short8*)(whhS + (gt * 64 + rbase) * 64 + (((4 + q) ^ sw) * 8));
      acc[gt] = mfma_bf(ah1, hb1, acc[gt]);
    }
#pragma unroll
    for (int gt = 0; gt < 4; ++gt) {
      const short8 ax1 =
          *(const short8*)(wihS + (gt * 64 + rbase) * 64 + (((4 + q) ^ sw) * 8));
      acc[gt] = mfma_bf(ax1, xb1, acc[gt]);
    }
    u32 hpk[2];
#pragma unroll
    for (int p = 0; p < 2; ++p) {
      const floatx2 iv = {acc[0][2 * p], acc[0][2 * p + 1]};
      const floatx2 fv = {acc[1][2 * p], acc[1][2 * p + 1]};
      const floatx2 gv = {acc[2][2 * p], acc[2][2 * p + 1]};
      const floatx2 ov = {acc[3][2 * p], acc[3][2 * p + 1]};
      const floatx2 ei = exp2v(iv * -L2E);
      const floatx2 ef = exp2v(fv * -L2E);
      const floatx2 eg = exp2v(gv * (2.0f * L2E));
      const floatx2 eo = exp2v(ov * -L2E);
      const floatx2 A = ei + 1.0f;   // 1/sig(i)
      const floatx2 F = ef + 1.0f;   // 1/sig(f)
      const floatx2 Bg = eg + 1.0f;  // tanh(g) = (eg-1)/Bg
      const floatx2 P = A * Bg;
      const floatx2 num = c[tq][p] * P + (eg - 1.0f) * F;
      const floatx2 cn = num * rcp2(F * P);
      c[tq][p] = cn;
      const floatx2 ec = exp2v(cn * (2.0f * L2E));
      const floatx2 h = (ec - 1.0f) * rcp2((eo + 1.0f) * (ec + 1.0f));
      hpk[p] = (u32)f2bf(h.x) | ((u32)f2bf(h.y) << 16);
    }
    // write h units tq*16+q*4..+3 of sample l16 (block 2tq+(q>>1), half q&1)
    *(u32x2*)(hw + l16 * 64 + (((2 * tq + (q >> 1)) ^ sw) * 8) + (q & 1) * 4) =
        u32x2{hpk[0], hpk[1]};
  }
}

// (256,2): arch half = 128 regs; transient peak ~100 with the unroll cap.
// LDS 73.5 KB -> 2 blocks/CU, 8 waves/CU, barrier-free drift.
__global__ void __launch_bounds__(NTHREADS, 2)
lstm_kernel(const float* __restrict__ obs_rel,
            const float* __restrict__ enc_emb_w, const float* __restrict__ enc_emb_b,
            const float* __restrict__ enc_w_ih, const float* __restrict__ enc_w_hh,
            const float* __restrict__ enc_b_ih, const float* __restrict__ enc_b_hh,
            const float* __restrict__ dec_emb_w, const float* __restrict__ dec_emb_b,
            const float* __restrict__ dec_w_ih, const float* __restrict__ dec_w_hh,
            const float* __restrict__ dec_b_ih, const float* __restrict__ dec_b_hh,
            const float* __restrict__ h2p_w, const float* __restrict__ h2p_b,
            float* __restrict__ out, int batch) {
  __shared__ __align__(16) u16 whhS[256 * 64];  // 32 KB swizzled bf16 W_hh
  __shared__ __align__(16) u16 wihS[256 * 64];  // 32 KB swizzled bf16 W_ih
  __shared__ __align__(16) u16 hS[4][16 * 64];  // 8 KB wave-private h
  __shared__ __align__(16) float biasS[256];    // current-phase gate bias
  __shared__ __align__(16) u32 ewpkS[64];       // current-phase packed emb w
  __shared__ __align__(16) float ebvS[64];      // current-phase emb bias

  const int tid = threadIdx.x;
  const int wv = tid >> 6, lane = tid & 63;
  const int q = lane >> 4, l16 = lane & 15;
  const long S0 = (long)blockIdx.x * 64;

  stage_w(enc_w_hh, whhS, tid);
  stage_w(enc_w_ih, wihS, tid);
  biasS[tid] = enc_b_ih[tid] + enc_b_hh[tid];
  if (tid < 64) {
    ewpkS[tid] = (u32)f2bf(enc_emb_w[tid * 2]) |
                 ((u32)f2bf(enc_emb_w[tid * 2 + 1]) << 16);
    ebvS[tid] = enc_emb_b[tid];
  }
  for (int i = tid; i < 4 * 16 * 64 / 2; i += NTHREADS) ((u32*)&hS[0][0])[i] = 0;

  short8 aex[2];
  floatx2 c[4][2];
#pragma unroll
  for (int t = 0; t < 4; ++t) c[t][0] = c[t][1] = floatx2{0.f, 0.f};
  aex[0] = aex[1] = short8{0, 0, 0, 0, 0, 0, 0, 0};
  const float b2p0 = h2p_b[0], b2p1 = h2p_b[1];
  u16* hw = &hS[wv][0];
  __syncthreads();  // staging visible; no more barriers until phase switch

  // ---- encoder: 8 steps, barrier-free (pos read straight from global, L2-warm)
#pragma unroll 1
  for (int t = 0; t < OBS_LEN; ++t)
    step<false>(hw, whhS, wihS, biasS, ewpkS, ebvS,
                obs_rel + (long)t * batch * 2 + (S0 + wv * 16) * 2,
                aex, c, nullptr, b2p0, b2p1, q, l16);

  // ---- phase switch: restage decoder weights/tables (2 barriers total)
  __syncthreads();
  stage_w(dec_w_hh, whhS, tid);
  stage_w(dec_w_ih, wihS, tid);
  biasS[tid] = dec_b_ih[tid] + dec_b_hh[tid];
  if (tid < 64) {
    ewpkS[tid] = (u32)f2bf(dec_emb_w[tid * 2]) |
                 ((u32)f2bf(dec_emb_w[tid * 2 + 1]) << 16);
    ebvS[tid] = dec_emb_b[tid];
  }
  __syncthreads();
#pragma unroll
  for (int t = 0; t < 4; ++t) c[t][0] = c[t][1] = floatx2{0.f, 0.f};
#pragma unroll
  for (int kf = 0; kf < 2; ++kf) {
    short8 a = {0, 0, 0, 0, 0, 0, 0, 0};
    if (l16 < 2) {
      const float* src = h2p_w + l16 * 64 + kf * 32 + q * 8;
#pragma unroll
      for (int j = 0; j < 8; ++j) a[j] = (short)f2bf(src[j]);
    }
    aex[kf] = a;
  }

  // decoder step 0: x = emb_dec(bf16(last_rel)), h = h_enc, c = 0
  step<false>(hw, whhS, wihS, biasS, ewpkS, ebvS,
              obs_rel + (long)7 * batch * 2 + (S0 + wv * 16) * 2,
              aex, c, nullptr, b2p0, b2p1, q, l16);

  // decoder steps 1..11: rel_{j-1} via aex-MFMA -> out + feedback, barrier-free
#pragma unroll 1
  for (int j = 1; j < PRED_LEN; ++j)
    step<true>(hw, whhS, wihS, biasS, ewpkS, ebvS, nullptr, aex, c,
               out + (long)(j - 1) * batch * 2 + (S0 + wv * 16) * 2,
               b2p0, b2p1, q, l16);

  // ---- trailing output: rel_pos[11] from h_12
  {
    const int sw = l16 & 7;
    const u16* hr = hw + l16 * 64;
    const short8 hb0 = *(const short8*)(hr + ((q ^ sw) * 8));
    const short8 hb1 = *(const short8*)(hr + (((4 + q) ^ sw) * 8));
    floatx4 z = {0.f, 0.f, 0.f, 0.f};
    z = mfma_bf(aex[0], hb0, z);
    z = mfma_bf(aex[1], hb1, z);
    if (q == 0) {
      float* outp = out + (long)(PRED_LEN - 1) * batch * 2 + (S0 + wv * 16) * 2;
      *(floatx2*)(outp + l16 * 2) = floatx2{z[0] + b2p0, z[1] + b2p1};
    }
  }
}

extern "C" void kernel_launch(void* const* d_in, const int* in_sizes, int n_in,
                              void* d_out, int out_size, void* d_ws, size_t ws_size,
                              hipStream_t stream) {
  const float* obs_rel = (const float*)d_in[1];
  const int batch = in_sizes[1] / (OBS_LEN * 2);  // 65536

  const int blocks = batch / 64;  // 1024
  hipLaunchKernelGGL(lstm_kernel, dim3(blocks), dim3(NTHREADS), 0, stream,
                     obs_rel,
                     (const float*)d_in[2], (const float*)d_in[3],
                     (const float*)d_in[4], (const float*)d_in[5],
                     (const float*)d_in[6], (const float*)d_in[7],
                     (const float*)d_in[8], (const float*)d_in[9],
                     (const float*)d_in[10], (const float*)d_in[11],
                     (const float*)d_in[12], (const float*)d_in[13],
                     (const float*)d_in[14], (const float*)d_in[15],
                     (float*)d_out, batch);
}

// Round 16
// 235.715 us; speedup vs baseline: 3.5271x; 1.0195x over previous
//
#include <hip/hip_runtime.h>

#define OBS_LEN 8
#define PRED_LEN 12
#define NTHREADS 256
// 4 waves/block; each wave owns TWO independent 16-sample groups (A/B) and
// alternates their steps -> software pipelining hides the per-step serial
// latency (h write -> read -> MFMA -> trans) that TLP could not (R15: 2
// waves/SIMD, VALUBusy pinned 47% barriered or not). No recurrence barriers.

typedef __attribute__((ext_vector_type(8))) short short8;  // 8 bf16
typedef __attribute__((ext_vector_type(4))) float floatx4;
typedef __attribute__((ext_vector_type(2))) float floatx2;
typedef __attribute__((ext_vector_type(4))) unsigned int u32x4;
typedef __attribute__((ext_vector_type(2))) unsigned int u32x2;
typedef unsigned short u16;
typedef unsigned int u32;

#define L2E 1.442695040888963f

__device__ __forceinline__ u16 f2bf(float f) {
  __bf16 b = (__bf16)f;
  return __builtin_bit_cast(u16, b);
}
__device__ __forceinline__ float bf2f(u16 h) {
  return __builtin_bit_cast(float, ((u32)h) << 16);
}
__device__ __forceinline__ float rndbf(float f) { return (float)(__bf16)f; }

#if __has_builtin(__builtin_amdgcn_exp2f)
__device__ __forceinline__ float fexp2_(float x) { return __builtin_amdgcn_exp2f(x); }
#else
__device__ __forceinline__ float fexp2_(float x) { return exp2f(x); }
#endif
__device__ __forceinline__ floatx2 exp2v(floatx2 x) {
  floatx2 r;
  r.x = fexp2_(x.x);
  r.y = fexp2_(x.y);
  return r;
}
#if __has_builtin(__builtin_amdgcn_rcpf)
__device__ __forceinline__ floatx2 rcp2(floatx2 x) {  // raw v_rcp ~1ulp
  floatx2 r;
  r.x = __builtin_amdgcn_rcpf(x.x);
  r.y = __builtin_amdgcn_rcpf(x.y);
  return r;
}
#else
__device__ __forceinline__ floatx2 rcp2(floatx2 x) {
  return floatx2{1.0f / x.x, 1.0f / x.y};
}
#endif

__device__ __forceinline__ floatx4 mfma_bf(short8 a, short8 b, floatx4 c) {
  return __builtin_amdgcn_mfma_f32_16x16x32_bf16(a, b, c, 0, 0, 0);
}

// Stage bf16(W) into LDS with per-row XOR block swizzle (16B block b of row r
// stored at b^(r&7)): step-time read lanes land <=2-way per bank (free).
__device__ __forceinline__ void stage_w(const float* __restrict__ W,
                                        u16* __restrict__ dst, int tid) {
  const float* src = W + tid * 64;
  u16* d = dst + tid * 64;
  const int rs = tid & 7;
#pragma unroll
  for (int b = 0; b < 8; ++b) {
    const floatx4 w0 = *(const floatx4*)(src + b * 8);
    const floatx4 w1 = *(const floatx4*)(src + b * 8 + 4);
    short8 v;
#pragma unroll
    for (int j = 0; j < 4; ++j) {
      v[j] = (short)f2bf(w0[j]);
      v[j + 4] = (short)f2bf(w1[j]);
    }
    *(short8*)(d + ((b ^ rs) * 8)) = v;
  }
}

// One LSTM step for ONE 16-sample group, NO barrier. h wave-private in LDS
// (same-wave ds ordering = program order), x in-register, rel via 2 aex-MFMAs,
// W streamed from the block-shared swizzled LDS image. Emb/bias tables come
// from the d_ws global image (L1-hot) -- moved out of LDS to hit the exact
// 80KB 2-blocks/CU boundary. tq loop FORCED non-unrolled (R13/R14: full unroll
// lets the scheduler hoist 64 ds_read_b128 -> arch-half exhaustion -> spill).
template <bool REL>
__device__ __forceinline__ void step(
    u16* __restrict__ hw,
    const u16* __restrict__ whhS, const u16* __restrict__ wihS,
    const float* __restrict__ biasG,
    const u32* __restrict__ ewpkG, const float* __restrict__ ebvG,
    const float* __restrict__ posrow,
    const short8 (&aex)[2], floatx2 (&c)[4][2],
    float* __restrict__ outp, float b2p0, float b2p1,
    int q, int l16) {
  const int sw = l16 & 7;
  const u16* hr = hw + l16 * 64;
  const short8 hb0 = *(const short8*)(hr + ((q ^ sw) * 8));
  const short8 hb1 = *(const short8*)(hr + (((4 + q) ^ sw) * 8));
  float rb0, rb1;
  if (REL) {
    floatx4 z = {0.f, 0.f, 0.f, 0.f};
    z = mfma_bf(aex[0], hb0, z);
    z = mfma_bf(aex[1], hb1, z);
    const float r0 = __shfl(z[0], l16) + b2p0;  // rel rows live on q==0 lanes
    const float r1 = __shfl(z[1], l16) + b2p1;
    if (q == 0) *(floatx2*)(outp + l16 * 2) = floatx2{r0, r1};
    rb0 = rndbf(r0);
    rb1 = rndbf(r1);
  } else {
    const floatx2 rr = *(const floatx2*)(posrow + l16 * 2);
    rb0 = rndbf(rr.x);
    rb1 = rndbf(rr.y);
  }
  // x B-frags in-register for k-slices [8q,8q+8) and [32+8q,+8) of this sample
  short8 xb0, xb1;
  {
    const u32x4 e0a = *(const u32x4*)(ewpkG + q * 8);
    const u32x4 e0b = *(const u32x4*)(ewpkG + q * 8 + 4);
    const u32x4 e1a = *(const u32x4*)(ewpkG + 32 + q * 8);
    const u32x4 e1b = *(const u32x4*)(ewpkG + 32 + q * 8 + 4);
    const floatx4 b0a = *(const floatx4*)(ebvG + q * 8);
    const floatx4 b0b = *(const floatx4*)(ebvG + q * 8 + 4);
    const floatx4 b1a = *(const floatx4*)(ebvG + 32 + q * 8);
    const floatx4 b1b = *(const floatx4*)(ebvG + 32 + q * 8 + 4);
#pragma unroll
    for (int j = 0; j < 4; ++j) {
      u32 p = e0a[j];
      xb0[j] = (short)f2bf(rb0 * bf2f((u16)(p & 0xffffu)) +
                           (rb1 * bf2f((u16)(p >> 16)) + b0a[j]));
      p = e0b[j];
      xb0[j + 4] = (short)f2bf(rb0 * bf2f((u16)(p & 0xffffu)) +
                               (rb1 * bf2f((u16)(p >> 16)) + b0b[j]));
      p = e1a[j];
      xb1[j] = (short)f2bf(rb0 * bf2f((u16)(p & 0xffffu)) +
                           (rb1 * bf2f((u16)(p >> 16)) + b1a[j]));
      p = e1b[j];
      xb1[j + 4] = (short)f2bf(rb0 * bf2f((u16)(p & 0xffffu)) +
                               (rb1 * bf2f((u16)(p >> 16)) + b1b[j]));
    }
  }
  // tile-quad loop: gates i,f,g,o of units tq*16+q*4+{0..3} for sample l16
#pragma unroll 1
  for (int tq = 0; tq < 4; ++tq) {
    const int rbase = tq * 16 + l16;
    floatx4 acc[4];
#pragma unroll
    for (int gt = 0; gt < 4; ++gt) {
      const floatx4 bias = *(const floatx4*)(biasG + gt * 64 + tq * 16 + q * 4);
      const short8 ah0 =
          *(const short8*)(whhS + (gt * 64 + rbase) * 64 + ((q ^ sw) * 8));
      acc[gt] = mfma_bf(ah0, hb0, bias);
    }
#pragma unroll
    for (int gt = 0; gt < 4; ++gt) {
      const short8 ax0 =
          *(const short8*)(wihS + (gt * 64 + rbase) * 64 + ((q ^ sw) * 8));
      acc[gt] = mfma_bf(ax0, xb0, acc[gt]);
    }
#pragma unroll
    for (int gt = 0; gt < 4; ++gt) {
      const short8 ah1 =
          *(const short8*)(whhS + (gt * 64 + rbase) * 64 + (((4 + q) ^ sw) * 8));
      acc[gt] = mfma_bf(ah1, hb1, acc[gt]);
    }
#pragma unroll
    for (int gt = 0; gt < 4; ++gt) {
      const short8 ax1 =
          *(const short8*)(wihS + (gt * 64 + rbase) * 64 + (((4 + q) ^ sw) * 8));
      acc[gt] = mfma_bf(ax1, xb1, acc[gt]);
    }
    u32 hpk[2];
#pragma unroll
    for (int p = 0; p < 2; ++p) {
      const floatx2 iv = {acc[0][2 * p], acc[0][2 * p + 1]};
      const floatx2 fv = {acc[1][2 * p], acc[1][2 * p + 1]};
      const floatx2 gv = {acc[2][2 * p], acc[2][2 * p + 1]};
      const floatx2 ov = {acc[3][2 * p], acc[3][2 * p + 1]};
      const floatx2 ei = exp2v(iv * -L2E);
      const floatx2 ef = exp2v(fv * -L2E);
      const floatx2 eg = exp2v(gv * (2.0f * L2E));
      const floatx2 eo = exp2v(ov * -L2E);
      const floatx2 A = ei + 1.0f;   // 1/sig(i)
      const floatx2 F = ef + 1.0f;   // 1/sig(f)
      const floatx2 Bg = eg + 1.0f;  // tanh(g) = (eg-1)/Bg
      const floatx2 P = A * Bg;
      const floatx2 num = c[tq][p] * P + (eg - 1.0f) * F;
      const floatx2 cn = num * rcp2(F * P);
      c[tq][p] = cn;
      const floatx2 ec = exp2v(cn * (2.0f * L2E));
      const floatx2 h = (ec - 1.0f) * rcp2((eo + 1.0f) * (ec + 1.0f));
      hpk[p] = (u32)f2bf(h.x) | ((u32)f2bf(h.y) << 16);
    }
    // write h units tq*16+q*4..+3 of sample l16 (block 2tq+(q>>1), half q&1)
    *(u32x2*)(hw + l16 * 64 + (((2 * tq + (q >> 1)) ^ sw) * 8) + (q & 1) * 4) =
        u32x2{hpk[0], hpk[1]};
  }
}

// d_ws image (floats): [0..255] biasE  [256..511] biasD
//                      [512..575](u32) ewpkE  [576..639](u32) ewpkD
//                      [640..703] ebvE  [704..767] ebvD
__global__ void prep_kernel(const float* __restrict__ eew, const float* __restrict__ eeb,
                            const float* __restrict__ ebi, const float* __restrict__ ebh,
                            const float* __restrict__ dew, const float* __restrict__ deb,
                            const float* __restrict__ dbi, const float* __restrict__ dbh,
                            float* __restrict__ ws) {
  const int t = threadIdx.x;
  ws[t] = ebi[t] + ebh[t];
  ws[256 + t] = dbi[t] + dbh[t];
  if (t < 64) {
    ((u32*)ws)[512 + t] =
        (u32)f2bf(eew[t * 2]) | ((u32)f2bf(eew[t * 2 + 1]) << 16);
    ((u32*)ws)[576 + t] =
        (u32)f2bf(dew[t * 2]) | ((u32)f2bf(dew[t * 2 + 1]) << 16);
    ws[640 + t] = eeb[t];
    ws[704 + t] = deb[t];
  }
}

// (256,2): 128 arch regs; persistent cA+cB(32)+aex(8)+misc, transient peak
// ~110 -> no spill (gate: WRITE_SIZE). LDS = 64K weights + 16K h = 81920 B
// exactly -> 2 blocks/CU. 512 blocks = one full resident round, no tail.
__global__ void __launch_bounds__(NTHREADS, 2)
lstm_kernel(const float* __restrict__ obs_rel,
            const float* __restrict__ enc_w_ih, const float* __restrict__ enc_w_hh,
            const float* __restrict__ dec_w_ih, const float* __restrict__ dec_w_hh,
            const float* __restrict__ h2p_w, const float* __restrict__ h2p_b,
            const float* __restrict__ ws,
            float* __restrict__ out, int batch) {
  __shared__ __align__(16) u16 whhS[256 * 64];     // 32 KB swizzled bf16 W_hh
  __shared__ __align__(16) u16 wihS[256 * 64];     // 32 KB swizzled bf16 W_ih
  __shared__ __align__(16) u16 hS[4][2][16 * 64];  // 16 KB wave-private h (A/B)

  const int tid = threadIdx.x;
  const int wv = tid >> 6, lane = tid & 63;
  const int q = lane >> 4, l16 = lane & 15;
  const long S0 = (long)blockIdx.x * 128;
  const long sA = S0 + wv * 32, sB = sA + 16;  // group sample bases

  stage_w(enc_w_hh, whhS, tid);
  stage_w(enc_w_ih, wihS, tid);
  for (int i = tid; i < 4 * 2 * 16 * 64 / 2; i += NTHREADS)
    ((u32*)&hS[0][0][0])[i] = 0;

  const float* biasE = ws;
  const float* biasD = ws + 256;
  const u32* ewpkE = (const u32*)ws + 512;
  const u32* ewpkD = (const u32*)ws + 576;
  const float* ebvE = ws + 640;
  const float* ebvD = ws + 704;

  short8 aex[2];
  floatx2 cA[4][2], cB[4][2];
#pragma unroll
  for (int t = 0; t < 4; ++t) {
    cA[t][0] = cA[t][1] = floatx2{0.f, 0.f};
    cB[t][0] = cB[t][1] = floatx2{0.f, 0.f};
  }
  aex[0] = aex[1] = short8{0, 0, 0, 0, 0, 0, 0, 0};
  const float b2p0 = h2p_b[0], b2p1 = h2p_b[1];
  u16* hwA = &hS[wv][0][0];
  u16* hwB = &hS[wv][1][0];
  __syncthreads();  // staging visible; no more barriers until phase switch

  // ---- encoder: 8 steps x 2 interleaved groups, barrier-free
#pragma unroll 1
  for (int t = 0; t < OBS_LEN; ++t) {
    const float* prow = obs_rel + (long)t * batch * 2;
    step<false>(hwA, whhS, wihS, biasE, ewpkE, ebvE, prow + sA * 2,
                aex, cA, nullptr, b2p0, b2p1, q, l16);
    step<false>(hwB, whhS, wihS, biasE, ewpkE, ebvE, prow + sB * 2,
                aex, cB, nullptr, b2p0, b2p1, q, l16);
  }

  // ---- phase switch: restage decoder weights (2 barriers total)
  __syncthreads();
  stage_w(dec_w_hh, whhS, tid);
  stage_w(dec_w_ih, wihS, tid);
  __syncthreads();
#pragma unroll
  for (int t = 0; t < 4; ++t) {
    cA[t][0] = cA[t][1] = floatx2{0.f, 0.f};
    cB[t][0] = cB[t][1] = floatx2{0.f, 0.f};
  }
#pragma unroll
  for (int kf = 0; kf < 2; ++kf) {
    short8 a = {0, 0, 0, 0, 0, 0, 0, 0};
    if (l16 < 2) {
      const float* src = h2p_w + l16 * 64 + kf * 32 + q * 8;
#pragma unroll
      for (int j = 0; j < 8; ++j) a[j] = (short)f2bf(src[j]);
    }
    aex[kf] = a;
  }

  // decoder step 0: x = emb_dec(bf16(last_rel)), h = h_enc, c = 0
  {
    const float* prow = obs_rel + (long)7 * batch * 2;
    step<false>(hwA, whhS, wihS, biasD, ewpkD, ebvD, prow + sA * 2,
                aex, cA, nullptr, b2p0, b2p1, q, l16);
    step<false>(hwB, whhS, wihS, biasD, ewpkD, ebvD, prow + sB * 2,
                aex, cB, nullptr, b2p0, b2p1, q, l16);
  }

  // decoder steps 1..11: rel_{j-1} via aex-MFMA -> out + feedback, barrier-free
#pragma unroll 1
  for (int j = 1; j < PRED_LEN; ++j) {
    float* orow = out + (long)(j - 1) * batch * 2;
    step<true>(hwA, whhS, wihS, biasD, ewpkD, ebvD, nullptr, aex, cA,
               orow + sA * 2, b2p0, b2p1, q, l16);
    step<true>(hwB, whhS, wihS, biasD, ewpkD, ebvD, nullptr, aex, cB,
               orow + sB * 2, b2p0, b2p1, q, l16);
  }

  // ---- trailing output: rel_pos[11] from h_12 (both groups)
  {
    float* orow = out + (long)(PRED_LEN - 1) * batch * 2;
    const int sw = l16 & 7;
#pragma unroll
    for (int g = 0; g < 2; ++g) {
      const u16* hr = (g ? hwB : hwA) + l16 * 64;
      const short8 hb0 = *(const short8*)(hr + ((q ^ sw) * 8));
      const short8 hb1 = *(const short8*)(hr + (((4 + q) ^ sw) * 8));
      floatx4 z = {0.f, 0.f, 0.f, 0.f};
      z = mfma_bf(aex[0], hb0, z);
      z = mfma_bf(aex[1], hb1, z);
      if (q == 0) {
        float* outp = orow + (g ? sB : sA) * 2;
        *(floatx2*)(outp + l16 * 2) = floatx2{z[0] + b2p0, z[1] + b2p1};
      }
    }
  }
}

extern "C" void kernel_launch(void* const* d_in, const int* in_sizes, int n_in,
                              void* d_out, int out_size, void* d_ws, size_t ws_size,
                              hipStream_t stream) {
  const float* obs_rel = (const float*)d_in[1];
  const int batch = in_sizes[1] / (OBS_LEN * 2);  // 65536
  float* ws = (float*)d_ws;

  hipLaunchKernelGGL(prep_kernel, dim3(1), dim3(256), 0, stream,
                     (const float*)d_in[2], (const float*)d_in[3],
                     (const float*)d_in[6], (const float*)d_in[7],
                     (const float*)d_in[8], (const float*)d_in[9],
                     (const float*)d_in[12], (const float*)d_in[13], ws);

  const int blocks = batch / 128;  // 512 = 256 CU x 2 -> one resident round
  hipLaunchKernelGGL(lstm_kernel, dim3(blocks), dim3(NTHREADS), 0, stream,
                     obs_rel,
                     (const float*)d_in[4], (const float*)d_in[5],
                     (const float*)d_in[10], (const float*)d_in[11],
                     (const float*)d_in[14], (const float*)d_in[15],
                     ws, (float*)d_out, batch);
}